// Round 9
// baseline (840.647 us; speedup 1.0000x reference)
//
#include <hip/hip_runtime.h>

typedef unsigned short u16;
typedef unsigned int u32;
typedef __attribute__((ext_vector_type(8))) short bf16x8;
typedef __attribute__((ext_vector_type(4))) float f32x4;

#define BKW 2048           // bucket width (nodes); BKSH = log2(BKW)
#define BKSH 11
#define MAXBK 512          // max total buckets (bench: 368)

__device__ __forceinline__ float bf2f(u16 u) { return __uint_as_float(((u32)u) << 16); }
__device__ __forceinline__ u16 f2bf(float f) {
  u32 u = __float_as_uint(f);
  return (u16)((u + 0x7fffu + ((u >> 16) & 1u)) >> 16);
}

// ---------------------------------------------------------------------------
// Fused embedding gather (all 3 node types, one launch): fp32 emb row ->
// bf16 feature row. 4 elems/thread (float4 load, ushort4 store).
__global__ void gather3(const float* __restrict__ eP, const int* __restrict__ iP,
                        u16* __restrict__ oP, int nP, int VP,
                        const float* __restrict__ eO, const int* __restrict__ iO,
                        u16* __restrict__ oO, int nO, int VO,
                        const float* __restrict__ eL, const int* __restrict__ iL,
                        u16* __restrict__ oL, int nL, int VL) {
  int u = blockIdx.x * 256 + threadIdx.x;
  int tP = nP * 16, tO = tP + nO * 16, tL = tO + nL * 16;
  const float* emb; const int* ids; u16* out; int V, lu;
  if (u < tP)      { emb = eP; ids = iP; out = oP; V = VP; lu = u; }
  else if (u < tO) { emb = eO; ids = iO; out = oO; V = VO; lu = u - tP; }
  else if (u < tL) { emb = eL; ids = iL; out = oL; V = VL; lu = u - tO; }
  else return;
  int node = lu >> 4, q = lu & 15;
  int r = ids[node];
  r = ((u32)r < (u32)V) ? r : 0;
  float4 v = *(const float4*)(emb + (size_t)r * 64 + q * 4);
  ushort4 o;
  o.x = f2bf(v.x); o.y = f2bf(v.y); o.z = f2bf(v.z); o.w = f2bf(v.w);
  *(ushort4*)(out + (size_t)node * 64 + q * 4) = o;
}

// ---------------------------------------------------------------------------
// Weight prep (once per launch): bf16 lin weights, bf16 root-sum weights,
// fp32 bias-sums.
__global__ void prep_w(const float* __restrict__ Wl, const float* __restrict__ Wr,
                       const float* __restrict__ bl,
                       u16* __restrict__ WBlin, u16* __restrict__ WBroot,
                       float* __restrict__ bsums) {
  int i = blockIdx.x * 256 + threadIdx.x;
  const int TL = 3 * 5 * 4096;
  if (i < TL) { WBlin[i] = f2bf(Wl[i]); return; }
  int j = i - TL;
  if (j < 3 * 3 * 4096) {
    int lt = j / (3 * 4096), rem = j % (3 * 4096), c = rem / 4096, e = rem % 4096;
    int r0 = (c == 0) ? 0 : (c == 1) ? 1 : 3;
    float v = Wr[((size_t)lt * 5 + r0) * 4096 + e];
    if (c == 0) v += Wr[((size_t)lt * 5 + 2) * 4096 + e] +
                     Wr[((size_t)lt * 5 + 4) * 4096 + e];
    WBroot[j] = f2bf(v);
    return;
  }
  int k2 = j - 3 * 3 * 4096;
  if (k2 < 3 * 3 * 64) {
    int lt = k2 / 192, rem = k2 % 192, c = rem / 64, e = rem % 64;
    int r0 = (c == 0) ? 0 : (c == 1) ? 1 : 3;
    float v = bl[((size_t)lt * 5 + r0) * 64 + e];
    if (c == 0) v += bl[((size_t)lt * 5 + 2) * 64 + e] +
                     bl[((size_t)lt * 5 + 4) * 64 + e];
    bsums[k2] = v;
  }
}

// ---------------------------------------------------------------------------
// CSR build, bucket-sort formulation (dense writes).
// ---------------------------------------------------------------------------
__global__ void __launch_bounds__(256) bkt_count(
    const int* __restrict__ D0, const int* __restrict__ D1, const int* __restrict__ D2,
    const int* __restrict__ D3, const int* __restrict__ D4,
    int* __restrict__ bcnt,
    int E1, int E2, int E3, int E4, int E5,
    int s1, int s2, int s3, int s4,
    int N0, int N1, int N2, int N3, int N4, int NBK) {
  __shared__ int c[MAXBK];
  int t = threadIdx.x;
  for (int i = t; i < NBK; i += 256) c[i] = 0;
  __syncthreads();
  int chunk0 = blockIdx.x * 8192;
  for (int j = 0; j < 32; j++) {
    int e = chunk0 + j * 256 + t;
    if (e >= E5) break;
    const int* dp; int sb, N, le;
    if (e < E1)      { dp = D0; sb = 0;  N = N0; le = e; }
    else if (e < E2) { dp = D1; sb = s1; N = N1; le = e - E1; }
    else if (e < E3) { dp = D2; sb = s2; N = N2; le = e - E2; }
    else if (e < E4) { dp = D3; sb = s3; N = N3; le = e - E3; }
    else             { dp = D4; sb = s4; N = N4; le = e - E4; }
    int d = dp[le];
    if ((u32)d < (u32)N) atomicAdd(&c[sb + (d >> BKSH)], 1);
  }
  __syncthreads();
  for (int i = t; i < NBK; i += 256) if (c[i]) atomicAdd(&bcnt[i], c[i]);
}

__global__ void __launch_bounds__(512) bkt_scan(
    const int* __restrict__ bcnt, int* __restrict__ bbase, int* __restrict__ bcur,
    int* __restrict__ off,
    int s1, int s2, int s3, int s4, int NBK,
    int q0, int q1, int q2, int q3, int q4) {   // absolute off-sentinel indices
  __shared__ int sb[MAXBK + 1];
  __shared__ int ws[8];
  int t = threadIdx.x, lane = t & 63, wv = t >> 6;
  int v = (t < NBK) ? bcnt[t] : 0;
  int s = v;
  #pragma unroll
  for (int d = 1; d < 64; d <<= 1) { int u = __shfl_up(s, d); if (lane >= d) s += u; }
  if (lane == 63) ws[wv] = s;
  __syncthreads();
  int wbase = 0;
  for (int i = 0; i < wv; i++) wbase += ws[i];
  int excl = wbase + (s - v);
  if (t < NBK) { bbase[t] = excl; bcur[t] = excl; sb[t] = excl; }
  if (t == 0) {
    int tot = 0;
    #pragma unroll
    for (int i = 0; i < 8; i++) tot += ws[i];
    bbase[NBK] = tot; sb[NBK] = tot;
  }
  __syncthreads();
  if (t == 0) off[q0] = sb[s1];
  else if (t == 1) off[q1] = sb[s2] - sb[s1];
  else if (t == 2) off[q2] = sb[s3] - sb[s2];
  else if (t == 3) off[q3] = sb[s4] - sb[s3];
  else if (t == 4) off[q4] = sb[NBK] - sb[s4];
}

__global__ void __launch_bounds__(256) bkt_scatter(
    const int* __restrict__ S0, const int* __restrict__ S1, const int* __restrict__ S2,
    const int* __restrict__ S3, const int* __restrict__ S4,
    const int* __restrict__ D0, const int* __restrict__ D1, const int* __restrict__ D2,
    const int* __restrict__ D3, const int* __restrict__ D4,
    int* __restrict__ bcur, u32* __restrict__ bdata,
    int E1, int E2, int E3, int E4, int E5,
    int s1, int s2, int s3, int s4,
    int N0, int N1, int N2, int N3, int N4, int NBK) {
  __shared__ int c[MAXBK];
  __shared__ int base[MAXBK];
  int t = threadIdx.x;
  for (int i = t; i < NBK; i += 256) c[i] = 0;
  __syncthreads();
  int chunk0 = blockIdx.x * 4096;
  int lb[16]; u32 rec[16];
  #pragma unroll
  for (int j = 0; j < 16; j++) {
    int e = chunk0 + j * 256 + t;
    lb[j] = -1;
    if (e < E5) {
      const int *sp, *dp; int sb, N, le;
      if (e < E1)      { sp = S0; dp = D0; sb = 0;  N = N0; le = e; }
      else if (e < E2) { sp = S1; dp = D1; sb = s1; N = N1; le = e - E1; }
      else if (e < E3) { sp = S2; dp = D2; sb = s2; N = N2; le = e - E2; }
      else if (e < E4) { sp = S3; dp = D3; sb = s3; N = N3; le = e - E3; }
      else             { sp = S4; dp = D4; sb = s4; N = N4; le = e - E4; }
      int d = dp[le];
      if ((u32)d < (u32)N) {
        lb[j] = sb + (d >> BKSH);
        rec[j] = ((u32)sp[le] << BKSH) | (u32)(d & (BKW - 1));
        atomicAdd(&c[lb[j]], 1);
      }
    }
  }
  __syncthreads();
  for (int i = t; i < NBK; i += 256) {
    int cc = c[i];
    base[i] = cc ? atomicAdd(&bcur[i], cc) : 0;
    c[i] = 0;
  }
  __syncthreads();
  #pragma unroll
  for (int j = 0; j < 16; j++) {
    if (lb[j] >= 0) {
      int r = atomicAdd(&c[lb[j]], 1);
      int pos = base[lb[j]] + r;
      if ((u32)pos < (u32)E5) bdata[pos] = rec[j];   // dense bucket frontier write
    }
  }
}

// 1024 threads/block: 368 blocks x 16 waves.
__global__ void __launch_bounds__(1024) bkt_sort(
    const int* __restrict__ bbase, const u32* __restrict__ bdata,
    int* __restrict__ off, int* __restrict__ csr,
    int s1, int s2, int s3, int s4, int NBK,
    int N0, int N1, int N2, int N3, int N4,
    int o1, int o2, int o3, int o4,
    int g1, int g2, int g3, int g4,
    int La, int Lu, int Lt) {
  __shared__ int cnt[BKW];
  __shared__ int pre[BKW];
  __shared__ int wsum[16];
  int b = blockIdx.x, t = threadIdx.x, lane = t & 63, wv = t >> 6;
  int r = (b >= s4) ? 4 : (b >= s3) ? 3 : (b >= s2) ? 2 : (b >= s1) ? 1 : 0;
  int sr = (r == 0) ? 0 : (r == 1) ? s1 : (r == 2) ? s2 : (r == 3) ? s3 : s4;
  int Nr = (r == 0) ? N0 : (r == 1) ? N1 : (r == 2) ? N2 : (r == 3) ? N3 : N4;
  int oR = (r == 0) ? 0 : (r == 1) ? o1 : (r == 2) ? o2 : (r == 3) ? o3 : o4;
  int gR = (r == 0) ? 0 : (r == 1) ? g1 : (r == 2) ? g2 : (r == 3) ? g3 : g4;
  int Lr = (r == 0) ? La : (r == 1 || r == 2) ? Lu : Lt;
  int relRecBase = bbase[sr];
  int bstart = bbase[b], bend = bbase[b + 1];
  int node0 = (b - sr) << BKSH;
  int W = Nr - node0; if (W > BKW) W = BKW;
  int csrB = bstart - relRecBase;              // base within relation csr segment
  for (int i = t; i < BKW; i += 1024) cnt[i] = 0;
  __syncthreads();
  for (int i = bstart + t; i < bend; i += 1024)
    atomicAdd(&cnt[bdata[i] & (BKW - 1)], 1);
  __syncthreads();
  // block exclusive scan over 2048 counts (2/thread)
  int basei = t * 2;
  int v0 = cnt[basei], v1 = cnt[basei + 1];
  int tsum = v0 + v1;
  int s = tsum;
  #pragma unroll
  for (int d = 1; d < 64; d <<= 1) { int u = __shfl_up(s, d); if (lane >= d) s += u; }
  if (lane == 63) wsum[wv] = s;
  __syncthreads();
  int wbase = 0;
  #pragma unroll
  for (int i = 0; i < 16; i++) wbase += (i < wv) ? wsum[i] : 0;
  int run = wbase + (s - tsum);
  pre[basei] = run;
  if (basei < W) off[oR + node0 + basei] = csrB + run;
  run += v0;
  pre[basei + 1] = run;
  if (basei + 1 < W) off[oR + node0 + basei + 1] = csrB + run;
  cnt[basei] = 0; cnt[basei + 1] = 0;          // reuse as rank cursor
  __syncthreads();
  for (int i = bstart + t; i < bend; i += 1024) {
    u32 rc = bdata[i];
    int ld = rc & (BKW - 1);
    int src = (int)(rc >> BKSH);
    int rank = atomicAdd(&cnt[ld], 1);
    int pos = csrB + pre[ld] + rank;
    if ((u32)pos < (u32)Lr) csr[gR + pos] = src;    // L2-resident bucket region
  }
}

// ---------------------------------------------------------------------------
// FUSED SAGE tile (device fn): vectorized gather + MFMA GEMM + epilogue.
// 32 dst rows, 4 waves. Gather: lane=(row-slot s, col-chunk c); one bf16x8
// (16B) per lane per edge-round. NEW: CSR offsets + first-round neighbor ids
// for ALL relations prefetched before any row load — one idx-load latency
// instead of NM serialized chains.
template <int NM>
__device__ __forceinline__ void sage_tile(
    u16* A_lds, u16* D_lds, int tile,
    const u16* __restrict__ X, u16* __restrict__ out,
    const u16* __restrict__ S0, const int* __restrict__ of0, const int* __restrict__ ix0, int ns0,
    const u16* __restrict__ S1, const int* __restrict__ of1, const int* __restrict__ ix1, int ns1,
    const u16* __restrict__ S2, const int* __restrict__ of2, const int* __restrict__ ix2, int ns2,
    const u16* __restrict__ lin0, const u16* __restrict__ lin1, const u16* __restrict__ lin2,
    const u16* __restrict__ root, const float* __restrict__ bsum,
    float scale, int n) {
  constexpr int KC = 2 * (NM + 1);            // K-chunks of 32
  constexpr int AP = (NM + 1) * 64 + 8;       // padded A row pitch (u16)
  int t = threadIdx.x, wave = t >> 6, lane = t & 63;
  int m0 = tile << 5;

  // ---- gather phase: lane (s,c); wave w fills rows w*8..w*8+7 ----
  {
    int c = lane & 7;
    int rr = wave * 8 + (lane >> 3);
    int g = m0 + rr;
    int gc = (g < n) ? g : (n - 1);
    bf16x8 xv = *(const bf16x8*)(X + (size_t)gc * 64 + c * 8);   // early issue
    int e0s[NM], e1s[NM];
    #pragma unroll
    for (int rel = 0; rel < NM; rel++) {       // all offset loads in flight
      const int* of = (rel == 0) ? of0 : (rel == 1) ? of1 : of2;
      e0s[rel] = of[gc];
      e1s[rel] = of[gc + 1];
    }
    int idp[NM][8];
    #pragma unroll
    for (int rel = 0; rel < NM; rel++) {       // all round-0 id loads in flight
      const int* ix = (rel == 0) ? ix0 : (rel == 1) ? ix1 : ix2;
      int e0 = e0s[rel], e1 = e1s[rel];
      #pragma unroll
      for (int j = 0; j < 8; j++) {
        int e = e0 + j;
        idp[rel][j] = (e < e1) ? ix[e] : -1;   // exec-masked load
      }
    }
    #pragma unroll
    for (int rel = 0; rel < NM; rel++) {
      const u16* S  = (rel == 0) ? S0 : (rel == 1) ? S1 : S2;
      const int* ix = (rel == 0) ? ix0 : (rel == 1) ? ix1 : ix2;
      u32 ns = (u32)((rel == 0) ? ns0 : (rel == 1) ? ns1 : ns2);
      int e0 = e0s[rel], e1 = e1s[rel];
      int deg = e1 - e0;
      float a[8] = {0.f, 0.f, 0.f, 0.f, 0.f, 0.f, 0.f, 0.f};
      #pragma unroll
      for (int j = 0; j < 8; j++) {            // round 0: prefetched ids
        bf16x8 v = {};
        if ((u32)idp[rel][j] < ns)
          v = *(const bf16x8*)(S + (size_t)(u32)idp[rel][j] * 64 + c * 8);
        #pragma unroll
        for (int k = 0; k < 8; k++) a[k] += bf2f((u16)v[k]);
      }
      for (int base = e0 + 8; __any(base < e1); base += 8) {   // rare tail
        int id[8];
        #pragma unroll
        for (int j = 0; j < 8; j++) {
          int e = base + j;
          id[j] = (e < e1) ? ix[e] : -1;
        }
        #pragma unroll
        for (int j = 0; j < 8; j++) {
          bf16x8 v = {};
          if ((u32)id[j] < ns)
            v = *(const bf16x8*)(S + (size_t)(u32)id[j] * 64 + c * 8);
          #pragma unroll
          for (int k = 0; k < 8; k++) a[k] += bf2f((u16)v[k]);
        }
      }
      float inv = (deg > 0) ? 1.f / (float)deg : 0.f;
      bf16x8 m8;
      #pragma unroll
      for (int k = 0; k < 8; k++) m8[k] = (short)f2bf(a[k] * inv);
      *(bf16x8*)&A_lds[rr * AP + rel * 64 + c * 8] = m8;
    }
    *(bf16x8*)&A_lds[rr * AP + NM * 64 + c * 8] = xv;          // root X row
  }
  __syncthreads();

  // ---- MFMA phase: wave w -> rows (w&1)*16..+16, cols (w>>1)*32..+32 ----
  int col0 = lane & 15, kb = lane >> 4;
  int rt = (wave & 1) * 16;
  int ct = (wave >> 1) * 32;
  const u16* Wbase[KC];
  #pragma unroll
  for (int kc = 0; kc < KC; kc++) {
    int m = kc >> 1;
    const u16* basep = (m < NM) ? ((m == 0) ? lin0 : (m == 1) ? lin1 : lin2) : root;
    Wbase[kc] = basep + (kc & 1) * 32 + kb * 8;
  }
  f32x4 acc0 = {}, acc1 = {};
  #pragma unroll
  for (int kc = 0; kc < KC; kc++) {
    bf16x8 Af = *(const bf16x8*)&A_lds[(rt + col0) * AP + kc * 32 + kb * 8];
    bf16x8 B0 = *(const bf16x8*)(Wbase[kc] + (ct + col0) * 64);        // L1 hot
    acc0 = __builtin_amdgcn_mfma_f32_16x16x32_bf16(Af, B0, acc0, 0, 0, 0);
    bf16x8 B1 = *(const bf16x8*)(Wbase[kc] + (ct + 16 + col0) * 64);
    acc1 = __builtin_amdgcn_mfma_f32_16x16x32_bf16(Af, B1, acc1, 0, 0, 0);
  }

  // ---- epilogue: v = relu((acc+b)*s) + x, staged via LDS for coalesced IO ----
  float b0 = bsum[ct + col0];
  float b1 = bsum[ct + 16 + col0];
  #pragma unroll
  for (int j = 0; j < 4; j++) {
    int dr = rt + kb * 4 + j;                // D row within 32-row tile
    float xv0 = bf2f(A_lds[dr * AP + NM * 64 + ct + col0]);
    D_lds[dr * 72 + ct + col0] = f2bf(fmaxf((acc0[j] + b0) * scale, 0.f) + xv0);
    float xv1 = bf2f(A_lds[dr * AP + NM * 64 + ct + 16 + col0]);
    D_lds[dr * 72 + ct + 16 + col0] = f2bf(fmaxf((acc1[j] + b1) * scale, 0.f) + xv1);
  }
  __syncthreads();
  int row32 = t >> 3, cc = (t & 7) * 8;      // 256 threads = 32 rows x 8 chunks
  int row = m0 + row32;
  if (row < n) {
    bf16x8 o8;
    #pragma unroll
    for (int j = 0; j < 8; j++) o8[j] = (short)D_lds[row32 * 72 + cc + j];
    *(bf16x8*)(out + (size_t)row * 64 + cc) = o8;       // 16B coalesced store
  }
}

// ---------------------------------------------------------------------------
// One launch per LAYER: grid = person-tiles + obj-tiles + loc-tiles.
// All three node types read ping inputs and write disjoint pong outputs, so
// they are hazard-free and can run CONCURRENTLY — obj/loc blocks fill the
// CUs during person blocks' gather-latency stalls (previously 3 serial
// launches: 97 + ~25 + ~12 us + launch gaps).
__global__ void __launch_bounds__(256, 4) sage_layer(
    int bP, int bO,
    const u16* Xp, u16* outp,
    const u16* pS0, const int* pof0, const int* pix0, int pns0,
    const u16* pS1, const int* pof1, const int* pix1, int pns1,
    const u16* pS2, const int* pof2, const int* pix2, int pns2,
    const u16* plin0, const u16* plin1, const u16* plin2,
    const u16* proot, const float* pbsum, int nP,
    const u16* Xo, u16* outo,
    const u16* oS0, const int* oof0, const int* oix0, int ons0,
    const u16* olin0, const u16* oroot, const float* obsum, int nO,
    const u16* Xl, u16* outl,
    const u16* lS0, const int* lof0, const int* lix0, int lns0,
    const u16* llin0, const u16* lroot, const float* lbsum, int nL) {
  __shared__ __align__(16) u16 A_lds[32 * 264];   // sized for NM=3 pitch
  __shared__ __align__(16) u16 D_lds[32 * 72];
  int b = blockIdx.x;
  if (b < bP) {
    sage_tile<3>(A_lds, D_lds, b, Xp, outp,
                 pS0, pof0, pix0, pns0, pS1, pof1, pix1, pns1,
                 pS2, pof2, pix2, pns2, plin0, plin1, plin2,
                 proot, pbsum, 1.f / 3.f, nP);
  } else if (b < bP + bO) {
    sage_tile<1>(A_lds, D_lds, b - bP, Xo, outo,
                 oS0, oof0, oix0, ons0,
                 (const u16*)0, (const int*)0, (const int*)0, 0,
                 (const u16*)0, (const int*)0, (const int*)0, 0,
                 olin0, (const u16*)0, (const u16*)0, oroot, obsum, 1.f, nO);
  } else {
    sage_tile<1>(A_lds, D_lds, b - bP - bO, Xl, outl,
                 lS0, lof0, lix0, lns0,
                 (const u16*)0, (const int*)0, (const int*)0, 0,
                 (const u16*)0, (const int*)0, (const int*)0, 0,
                 llin0, (const u16*)0, (const u16*)0, lroot, lbsum, 1.f, nL);
  }
}

// ---------------------------------------------------------------------------
// Column sums over bf16 features (graph-mean readout), vectorized.
__global__ void __launch_bounds__(256) colsum3(const u16* __restrict__ x, int n,
                                               float* __restrict__ gout) {
  __shared__ float part[64];
  int t = threadIdx.x;
  if (t < 64) part[t] = 0.f;
  __syncthreads();
  int lane = t & 63;
  int c = (lane & 7) * 8;
  int rs = blockIdx.x * 32 + (t >> 3);
  int stride = gridDim.x * 32;
  float a[8] = {0.f, 0.f, 0.f, 0.f, 0.f, 0.f, 0.f, 0.f};
  for (int r = rs; r < n; r += stride) {
    bf16x8 v = *(const bf16x8*)(x + (size_t)r * 64 + c);
    #pragma unroll
    for (int k = 0; k < 8; k++) a[k] += bf2f((u16)v[k]);
  }
  #pragma unroll
  for (int k = 0; k < 8; k++) {
    a[k] += __shfl_xor(a[k], 8);
    a[k] += __shfl_xor(a[k], 16);
    a[k] += __shfl_xor(a[k], 32);
  }
  if (lane < 8) {
    #pragma unroll
    for (int k = 0; k < 8; k++) atomicAdd(&part[lane * 8 + k], a[k]);
  }
  __syncthreads();
  if (t < 64) atomicAdd(&gout[t], part[t]);
}

// Crime head: out[0:20) as FP32
__global__ void __launch_bounds__(256) head2(const float* __restrict__ gsum,
    const float* __restrict__ Wc1, const float* __restrict__ bc1,
    const float* __restrict__ Wc2, const float* __restrict__ bc2,
    int NP, int NO, int NL, float* __restrict__ out) {
  __shared__ float g[192];
  __shared__ float h[64];
  int t = threadIdx.x;
  if (t < 192) {
    float d = (t < 64) ? (float)NP : (t < 128) ? (float)NO : (float)NL;
    g[t] = gsum[t] / d;
  }
  __syncthreads();
  if (t < 64) {
    float a = bc1[t];
    for (int k = 0; k < 192; k++) a += g[k] * Wc1[(size_t)t * 192 + k];
    h[t] = fmaxf(a, 0.f);
  }
  __syncthreads();
  if (t < 20) {
    float a = bc2[t];
    for (int k = 0; k < 64; k++) a += h[k] * Wc2[(size_t)t * 64 + k];
    out[t] = a;
  }
}

// Suspect head: out[i] as FP32 (out passed pre-offset by +20).
__global__ void __launch_bounds__(256) suspect2(const u16* __restrict__ p,
    const float* __restrict__ Ws1, const float* __restrict__ bs1,
    const float* __restrict__ Ws2, const float* __restrict__ bs2,
    float* __restrict__ out, int NP) {
  __shared__ float W1[2048];
  __shared__ float b1[32], w2[32];
  __shared__ float b2s;
  int t = threadIdx.x;
  #pragma unroll
  for (int i = 0; i < 8; i++) {
    int d = t + i * 256;
    W1[d] = Ws1[d];
  }
  if (t < 32) { b1[t] = bs1[t]; w2[t] = Ws2[t]; }
  if (t == 0) b2s = bs2[0];
  __syncthreads();
  int i = blockIdx.x * 256 + t;
  if (i >= NP) return;
  float x[64];
  #pragma unroll
  for (int q = 0; q < 8; q++) {
    bf16x8 v = *(const bf16x8*)(p + (size_t)i * 64 + q * 8);
    #pragma unroll
    for (int k = 0; k < 8; k++) x[q * 8 + k] = bf2f((u16)v[k]);
  }
  float sc = b2s;
  for (int j = 0; j < 32; j++) {
    float a = b1[j];
    const float* wr = &W1[j * 64];
    #pragma unroll
    for (int k = 0; k < 64; k++) a += x[k] * wr[k];
    sc += fmaxf(a, 0.f) * w2[j];
  }
  out[i] = sc;
}

// ---------------------------------------------------------------------------
extern "C" void kernel_launch(void* const* d_in, const int* in_sizes, int n_in,
                              void* d_out, int out_size, void* d_ws, size_t ws_size,
                              hipStream_t stream) {
  const int NP = in_sizes[0], NO = in_sizes[1], NL = in_sizes[2];
  const int Ea = in_sizes[3], Eu = in_sizes[5], Et = in_sizes[7];
  const int VP = in_sizes[9] / 64, VO = in_sizes[10] / 64, VL = in_sizes[11] / 64;

  const int* x_person   = (const int*)d_in[0];
  const int* x_object   = (const int*)d_in[1];
  const int* x_location = (const int*)d_in[2];
  const int* acts_src = (const int*)d_in[3];
  const int* acts_dst = (const int*)d_in[4];
  const int* uses_src = (const int*)d_in[5];
  const int* uses_dst = (const int*)d_in[6];
  const int* at_src   = (const int*)d_in[7];
  const int* at_dst   = (const int*)d_in[8];
  const float* person_emb   = (const float*)d_in[9];
  const float* object_emb   = (const float*)d_in[10];
  const float* location_emb = (const float*)d_in[11];
  const float* Wl  = (const float*)d_in[12];
  const float* bl  = (const float*)d_in[13];
  const float* Wr  = (const float*)d_in[14];
  const float* Wc1 = (const float*)d_in[15];
  const float* bc1 = (const float*)d_in[16];
  const float* Wc2 = (const float*)d_in[17];
  const float* bc2 = (const float*)d_in[18];
  const float* Ws1 = (const float*)d_in[19];
  const float* bs1 = (const float*)d_in[20];
  const float* Ws2 = (const float*)d_in[21];
  const float* bs2 = (const float*)d_in[22];
  float* out = (float*)d_out;

  // ---- bucket geometry (MAXBK guard: bench is 368) ----
  int B0 = (NP + BKW - 1) >> BKSH;
  int B1 = (NO + BKW - 1) >> BKSH;
  int B3 = (NL + BKW - 1) >> BKSH;
  int s1 = B0, s2 = s1 + B1, s3 = s2 + B0, s4 = s3 + B3, NBK = s4 + B0;
  if (NBK > MAXBK) return;   // out stays 0 -> visible failure signature

  // ---- workspace (16B aligned) ----
  char* w = (char*)d_ws;
  auto alloc = [&](size_t bytes) { char* r = w; w += (bytes + 15) & ~(size_t)15; return r; };
  u16* pA = (u16*)alloc((size_t)NP * 128);
  u16* pB = (u16*)alloc((size_t)NP * 128);
  u16* oA = (u16*)alloc((size_t)NO * 128);
  u16* oB = (u16*)alloc((size_t)NO * 128);
  u16* lA = (u16*)alloc((size_t)NL * 128);
  u16* lB = (u16*)alloc((size_t)NL * 128);
  float* gsum = (float*)alloc(192 * 4);
  const size_t CN = (size_t)3 * NP + NO + NL;
  int* off = (int*)alloc((CN + 8) * 4);
  int* bcnt  = (int*)alloc((MAXBK) * 4);
  int* bbase = (int*)alloc((MAXBK + 1) * 4);
  int* bcur  = (int*)alloc((MAXBK) * 4);
  const int E1 = Ea, E2 = E1 + Eu, E3 = E2 + Eu, E4 = E3 + Et, E5 = E4 + Et;
  u32* bdata = (u32*)alloc((size_t)E5 * 4);
  u16* WBlin  = (u16*)alloc((size_t)3 * 5 * 4096 * 2);
  u16* WBroot = (u16*)alloc((size_t)3 * 3 * 4096 * 2);
  float* bsums = (float*)alloc((size_t)3 * 3 * 64 * 4);
  int* csr = (int*)alloc((size_t)E5 * 4);
  size_t base_need = (size_t)(w - (char*)d_ws);
  (void)n_in; (void)out_size;
  // ws guard: if it fires, out stays 0 -> absmax == 0.118652 exactly (signature)
  if (base_need > ws_size) return;

  int o0 = 0, o1 = NP + 1, o2 = o1 + NO + 1, o3 = o2 + NP + 1, o4 = o3 + NL + 1;
  int g1 = Ea, g2 = Ea + Eu, g3 = Ea + 2 * Eu, g4 = Ea + 2 * Eu + Et;
  int* csr0 = csr;
  int* csr1 = csr + g1;
  int* csr2 = csr + g2;
  int* csr3 = csr + g3;
  int* csr4 = csr + g4;

  hipMemsetAsync(bcnt, 0, MAXBK * sizeof(int), stream);
  hipMemsetAsync(gsum, 0, 192 * sizeof(float), stream);

  prep_w<<<387, 256, 0, stream>>>(Wl, Wr, bl, WBlin, WBroot, bsums);

  int tg = (NP + NO + NL) * 16;
  gather3<<<(tg + 255) / 256, 256, 0, stream>>>(
      person_emb, x_person, pA, NP, VP,
      object_emb, x_object, oA, NO, VO,
      location_emb, x_location, lA, NL, VL);

  // ---- CSR build: bucket-sort (dense writes) ----
  bkt_count<<<(E5 + 8191) / 8192, 256, 0, stream>>>(
      acts_dst, uses_dst, uses_src, at_dst, at_src, bcnt,
      E1, E2, E3, E4, E5, s1, s2, s3, s4, NP, NO, NP, NL, NP, NBK);
  bkt_scan<<<1, 512, 0, stream>>>(bcnt, bbase, bcur, off,
      s1, s2, s3, s4, NBK,
      o0 + NP, o1 + NO, o2 + NP, o3 + NL, o4 + NP);
  bkt_scatter<<<(E5 + 4095) / 4096, 256, 0, stream>>>(
      acts_src, uses_src, uses_dst, at_src, at_dst,
      acts_dst, uses_dst, uses_src, at_dst, at_src,
      bcur, bdata, E1, E2, E3, E4, E5, s1, s2, s3, s4, NP, NO, NP, NL, NP, NBK);
  bkt_sort<<<NBK, 1024, 0, stream>>>(bbase, bdata, off, csr,
      s1, s2, s3, s4, NBK, NP, NO, NP, NL, NP,
      o1, o2, o3, o4, g1, g2, g3, g4, Ea, Eu, Et);

  // ---- 3 layers: ONE fused launch per layer (person+obj+loc concurrent) ----
  u16* pb[2] = {pA, pB};
  u16* ob[2] = {oA, oB};
  u16* lb[2] = {lA, lB};
  int bP = (NP + 31) / 32, bO = (NO + 31) / 32, bL = (NL + 31) / 32;
  int cu = 0;
  for (int t = 0; t < 3; t++) {
    u16 *pi = pb[cu], *po = pb[1 - cu];
    u16 *oi = ob[cu], *oo = ob[1 - cu];
    u16 *li = lb[cu], *lo = lb[1 - cu];
    sage_layer<<<bP + bO + bL, 256, 0, stream>>>(
        bP, bO,
        pi, po,
        pi, off + o0, csr0, NP,
        oi, off + o2, csr2, NO,
        li, off + o4, csr4, NL,
        WBlin + ((size_t)t * 5 + 0) * 4096,
        WBlin + ((size_t)t * 5 + 2) * 4096,
        WBlin + ((size_t)t * 5 + 4) * 4096,
        WBroot + ((size_t)t * 3 + 0) * 4096,
        bsums + ((size_t)t * 3 + 0) * 64, NP,
        oi, oo,
        pi, off + o1, csr1, NP,
        WBlin + ((size_t)t * 5 + 1) * 4096,
        WBroot + ((size_t)t * 3 + 1) * 4096,
        bsums + ((size_t)t * 3 + 1) * 64, NO,
        li, lo,
        pi, off + o3, csr3, NP,
        WBlin + ((size_t)t * 5 + 3) * 4096,
        WBroot + ((size_t)t * 3 + 2) * 4096,
        bsums + ((size_t)t * 3 + 2) * 64, NL);
    cu = 1 - cu;
  }
  const u16* pF = pb[cu];
  const u16* oF = ob[cu];
  const u16* lF = lb[cu];

  // ---- readout (FP32 output) ----
  colsum3<<<256, 256, 0, stream>>>(pF, NP, gsum);
  colsum3<<<128, 256, 0, stream>>>(oF, NO, gsum + 64);
  colsum3<<<64, 256, 0, stream>>>(lF, NL, gsum + 128);
  head2<<<1, 256, 0, stream>>>(gsum, Wc1, bc1, Wc2, bc2, NP, NO, NL, out);
  suspect2<<<(NP + 255) / 256, 256, 0, stream>>>(pF, Ws1, bs1, Ws2, bs2, out + 20, NP);
}

// Round 10
// 823.351 us; speedup vs baseline: 1.0210x; 1.0210x over previous
//
#include <hip/hip_runtime.h>

typedef unsigned short u16;
typedef unsigned int u32;
typedef __attribute__((ext_vector_type(8))) short bf16x8;
typedef __attribute__((ext_vector_type(4))) float f32x4;

#define BKW 2048           // bucket width (nodes); BKSH = log2(BKW)
#define BKSH 11
#define MAXBK 512          // max total buckets (bench: 368)

__device__ __forceinline__ float bf2f(u16 u) { return __uint_as_float(((u32)u) << 16); }
__device__ __forceinline__ u16 f2bf(float f) {
  u32 u = __float_as_uint(f);
  return (u16)((u + 0x7fffu + ((u >> 16) & 1u)) >> 16);
}

// ---------------------------------------------------------------------------
// Fused embedding gather (all 3 node types, one launch): fp32 emb row ->
// bf16 feature row. 4 elems/thread (float4 load, ushort4 store).
__global__ void gather3(const float* __restrict__ eP, const int* __restrict__ iP,
                        u16* __restrict__ oP, int nP, int VP,
                        const float* __restrict__ eO, const int* __restrict__ iO,
                        u16* __restrict__ oO, int nO, int VO,
                        const float* __restrict__ eL, const int* __restrict__ iL,
                        u16* __restrict__ oL, int nL, int VL) {
  int u = blockIdx.x * 256 + threadIdx.x;
  int tP = nP * 16, tO = tP + nO * 16, tL = tO + nL * 16;
  const float* emb; const int* ids; u16* out; int V, lu;
  if (u < tP)      { emb = eP; ids = iP; out = oP; V = VP; lu = u; }
  else if (u < tO) { emb = eO; ids = iO; out = oO; V = VO; lu = u - tP; }
  else if (u < tL) { emb = eL; ids = iL; out = oL; V = VL; lu = u - tO; }
  else return;
  int node = lu >> 4, q = lu & 15;
  int r = ids[node];
  r = ((u32)r < (u32)V) ? r : 0;
  float4 v = *(const float4*)(emb + (size_t)r * 64 + q * 4);
  ushort4 o;
  o.x = f2bf(v.x); o.y = f2bf(v.y); o.z = f2bf(v.z); o.w = f2bf(v.w);
  *(ushort4*)(out + (size_t)node * 64 + q * 4) = o;
}

// ---------------------------------------------------------------------------
// Weight prep (once per launch): bf16 lin weights, bf16 root-sum weights,
// fp32 bias-sums.
__global__ void prep_w(const float* __restrict__ Wl, const float* __restrict__ Wr,
                       const float* __restrict__ bl,
                       u16* __restrict__ WBlin, u16* __restrict__ WBroot,
                       float* __restrict__ bsums) {
  int i = blockIdx.x * 256 + threadIdx.x;
  const int TL = 3 * 5 * 4096;
  if (i < TL) { WBlin[i] = f2bf(Wl[i]); return; }
  int j = i - TL;
  if (j < 3 * 3 * 4096) {
    int lt = j / (3 * 4096), rem = j % (3 * 4096), c = rem / 4096, e = rem % 4096;
    int r0 = (c == 0) ? 0 : (c == 1) ? 1 : 3;
    float v = Wr[((size_t)lt * 5 + r0) * 4096 + e];
    if (c == 0) v += Wr[((size_t)lt * 5 + 2) * 4096 + e] +
                     Wr[((size_t)lt * 5 + 4) * 4096 + e];
    WBroot[j] = f2bf(v);
    return;
  }
  int k2 = j - 3 * 3 * 4096;
  if (k2 < 3 * 3 * 64) {
    int lt = k2 / 192, rem = k2 % 192, c = rem / 64, e = rem % 64;
    int r0 = (c == 0) ? 0 : (c == 1) ? 1 : 3;
    float v = bl[((size_t)lt * 5 + r0) * 64 + e];
    if (c == 0) v += bl[((size_t)lt * 5 + 2) * 64 + e] +
                     bl[((size_t)lt * 5 + 4) * 64 + e];
    bsums[k2] = v;
  }
}

// ---------------------------------------------------------------------------
// CSR build, bucket-sort formulation (dense writes).
// ---------------------------------------------------------------------------
__global__ void __launch_bounds__(256) bkt_count(
    const int* __restrict__ D0, const int* __restrict__ D1, const int* __restrict__ D2,
    const int* __restrict__ D3, const int* __restrict__ D4,
    int* __restrict__ bcnt,
    int E1, int E2, int E3, int E4, int E5,
    int s1, int s2, int s3, int s4,
    int N0, int N1, int N2, int N3, int N4, int NBK) {
  __shared__ int c[MAXBK];
  int t = threadIdx.x;
  for (int i = t; i < NBK; i += 256) c[i] = 0;
  __syncthreads();
  int chunk0 = blockIdx.x * 8192;
  for (int j = 0; j < 32; j++) {
    int e = chunk0 + j * 256 + t;
    if (e >= E5) break;
    const int* dp; int sb, N, le;
    if (e < E1)      { dp = D0; sb = 0;  N = N0; le = e; }
    else if (e < E2) { dp = D1; sb = s1; N = N1; le = e - E1; }
    else if (e < E3) { dp = D2; sb = s2; N = N2; le = e - E2; }
    else if (e < E4) { dp = D3; sb = s3; N = N3; le = e - E3; }
    else             { dp = D4; sb = s4; N = N4; le = e - E4; }
    int d = dp[le];
    if ((u32)d < (u32)N) atomicAdd(&c[sb + (d >> BKSH)], 1);
  }
  __syncthreads();
  for (int i = t; i < NBK; i += 256) if (c[i]) atomicAdd(&bcnt[i], c[i]);
}

__global__ void __launch_bounds__(512) bkt_scan(
    const int* __restrict__ bcnt, int* __restrict__ bbase, int* __restrict__ bcur,
    int* __restrict__ off,
    int s1, int s2, int s3, int s4, int NBK,
    int q0, int q1, int q2, int q3, int q4) {   // absolute off-sentinel indices
  __shared__ int sb[MAXBK + 1];
  __shared__ int ws[8];
  int t = threadIdx.x, lane = t & 63, wv = t >> 6;
  int v = (t < NBK) ? bcnt[t] : 0;
  int s = v;
  #pragma unroll
  for (int d = 1; d < 64; d <<= 1) { int u = __shfl_up(s, d); if (lane >= d) s += u; }
  if (lane == 63) ws[wv] = s;
  __syncthreads();
  int wbase = 0;
  for (int i = 0; i < wv; i++) wbase += ws[i];
  int excl = wbase + (s - v);
  if (t < NBK) { bbase[t] = excl; bcur[t] = excl; sb[t] = excl; }
  if (t == 0) {
    int tot = 0;
    #pragma unroll
    for (int i = 0; i < 8; i++) tot += ws[i];
    bbase[NBK] = tot; sb[NBK] = tot;
  }
  __syncthreads();
  if (t == 0) off[q0] = sb[s1];
  else if (t == 1) off[q1] = sb[s2] - sb[s1];
  else if (t == 2) off[q2] = sb[s3] - sb[s2];
  else if (t == 3) off[q3] = sb[s4] - sb[s3];
  else if (t == 4) off[q4] = sb[NBK] - sb[s4];
}

__global__ void __launch_bounds__(256) bkt_scatter(
    const int* __restrict__ S0, const int* __restrict__ S1, const int* __restrict__ S2,
    const int* __restrict__ S3, const int* __restrict__ S4,
    const int* __restrict__ D0, const int* __restrict__ D1, const int* __restrict__ D2,
    const int* __restrict__ D3, const int* __restrict__ D4,
    int* __restrict__ bcur, u32* __restrict__ bdata,
    int E1, int E2, int E3, int E4, int E5,
    int s1, int s2, int s3, int s4,
    int N0, int N1, int N2, int N3, int N4, int NBK) {
  __shared__ int c[MAXBK];
  __shared__ int base[MAXBK];
  int t = threadIdx.x;
  for (int i = t; i < NBK; i += 256) c[i] = 0;
  __syncthreads();
  int chunk0 = blockIdx.x * 4096;
  int lb[16]; u32 rec[16];
  #pragma unroll
  for (int j = 0; j < 16; j++) {
    int e = chunk0 + j * 256 + t;
    lb[j] = -1;
    if (e < E5) {
      const int *sp, *dp; int sb, N, le;
      if (e < E1)      { sp = S0; dp = D0; sb = 0;  N = N0; le = e; }
      else if (e < E2) { sp = S1; dp = D1; sb = s1; N = N1; le = e - E1; }
      else if (e < E3) { sp = S2; dp = D2; sb = s2; N = N2; le = e - E2; }
      else if (e < E4) { sp = S3; dp = D3; sb = s3; N = N3; le = e - E3; }
      else             { sp = S4; dp = D4; sb = s4; N = N4; le = e - E4; }
      int d = dp[le];
      if ((u32)d < (u32)N) {
        lb[j] = sb + (d >> BKSH);
        rec[j] = ((u32)sp[le] << BKSH) | (u32)(d & (BKW - 1));
        atomicAdd(&c[lb[j]], 1);
      }
    }
  }
  __syncthreads();
  for (int i = t; i < NBK; i += 256) {
    int cc = c[i];
    base[i] = cc ? atomicAdd(&bcur[i], cc) : 0;
    c[i] = 0;
  }
  __syncthreads();
  #pragma unroll
  for (int j = 0; j < 16; j++) {
    if (lb[j] >= 0) {
      int r = atomicAdd(&c[lb[j]], 1);
      int pos = base[lb[j]] + r;
      if ((u32)pos < (u32)E5) bdata[pos] = rec[j];   // dense bucket frontier write
    }
  }
}

// 1024 threads/block: 368 blocks x 16 waves.
__global__ void __launch_bounds__(1024) bkt_sort(
    const int* __restrict__ bbase, const u32* __restrict__ bdata,
    int* __restrict__ off, int* __restrict__ csr,
    int s1, int s2, int s3, int s4, int NBK,
    int N0, int N1, int N2, int N3, int N4,
    int o1, int o2, int o3, int o4,
    int g1, int g2, int g3, int g4,
    int La, int Lu, int Lt) {
  __shared__ int cnt[BKW];
  __shared__ int pre[BKW];
  __shared__ int wsum[16];
  int b = blockIdx.x, t = threadIdx.x, lane = t & 63, wv = t >> 6;
  int r = (b >= s4) ? 4 : (b >= s3) ? 3 : (b >= s2) ? 2 : (b >= s1) ? 1 : 0;
  int sr = (r == 0) ? 0 : (r == 1) ? s1 : (r == 2) ? s2 : (r == 3) ? s3 : s4;
  int Nr = (r == 0) ? N0 : (r == 1) ? N1 : (r == 2) ? N2 : (r == 3) ? N3 : N4;
  int oR = (r == 0) ? 0 : (r == 1) ? o1 : (r == 2) ? o2 : (r == 3) ? o3 : o4;
  int gR = (r == 0) ? 0 : (r == 1) ? g1 : (r == 2) ? g2 : (r == 3) ? g3 : g4;
  int Lr = (r == 0) ? La : (r == 1 || r == 2) ? Lu : Lt;
  int relRecBase = bbase[sr];
  int bstart = bbase[b], bend = bbase[b + 1];
  int node0 = (b - sr) << BKSH;
  int W = Nr - node0; if (W > BKW) W = BKW;
  int csrB = bstart - relRecBase;              // base within relation csr segment
  for (int i = t; i < BKW; i += 1024) cnt[i] = 0;
  __syncthreads();
  for (int i = bstart + t; i < bend; i += 1024)
    atomicAdd(&cnt[bdata[i] & (BKW - 1)], 1);
  __syncthreads();
  // block exclusive scan over 2048 counts (2/thread)
  int basei = t * 2;
  int v0 = cnt[basei], v1 = cnt[basei + 1];
  int tsum = v0 + v1;
  int s = tsum;
  #pragma unroll
  for (int d = 1; d < 64; d <<= 1) { int u = __shfl_up(s, d); if (lane >= d) s += u; }
  if (lane == 63) wsum[wv] = s;
  __syncthreads();
  int wbase = 0;
  #pragma unroll
  for (int i = 0; i < 16; i++) wbase += (i < wv) ? wsum[i] : 0;
  int run = wbase + (s - tsum);
  pre[basei] = run;
  if (basei < W) off[oR + node0 + basei] = csrB + run;
  run += v0;
  pre[basei + 1] = run;
  if (basei + 1 < W) off[oR + node0 + basei + 1] = csrB + run;
  cnt[basei] = 0; cnt[basei + 1] = 0;          // reuse as rank cursor
  __syncthreads();
  for (int i = bstart + t; i < bend; i += 1024) {
    u32 rc = bdata[i];
    int ld = rc & (BKW - 1);
    int src = (int)(rc >> BKSH);
    int rank = atomicAdd(&cnt[ld], 1);
    int pos = csrB + pre[ld] + rank;
    if ((u32)pos < (u32)Lr) csr[gR + pos] = src;    // L2-resident bucket region
  }
}

// ---------------------------------------------------------------------------
// FUSED SAGE layer: vectorized gather + MFMA GEMM + epilogue, ping-pong.
// Block = 32 dst rows, 4 waves (round-8 proven body, 36 VGPR).
// OCCUPANCY FIX: D staging reuses A_lds (relation-0 region is dead after the
// MFMA phase; an extra barrier orders residual-reads before the overwrite).
// LDS 21504 -> 16896 B and __launch_bounds__(256,8): 8 blocks/CU resident
// (was ~5 at 65% occupancy) to hide the L2/L3 gather latency.
template <int NM>
__global__ void __launch_bounds__(256, 8) sage_fused(
    const u16* __restrict__ X, u16* __restrict__ out,   // out != X (ping-pong)
    const u16* __restrict__ S0, const int* __restrict__ of0, const int* __restrict__ ix0, int ns0,
    const u16* __restrict__ S1, const int* __restrict__ of1, const int* __restrict__ ix1, int ns1,
    const u16* __restrict__ S2, const int* __restrict__ of2, const int* __restrict__ ix2, int ns2,
    const u16* __restrict__ lin0, const u16* __restrict__ lin1, const u16* __restrict__ lin2,
    const u16* __restrict__ root, const float* __restrict__ bsum,
    float scale, int n) {
  constexpr int KC = 2 * (NM + 1);            // K-chunks of 32
  constexpr int AP = (NM + 1) * 64 + 8;       // padded A row pitch (u16)
  __shared__ __align__(16) u16 A_lds[32 * AP];
  int t = threadIdx.x, wave = t >> 6, lane = t & 63;
  int m0 = blockIdx.x << 5;

  // ---- gather phase: lane (s,c); wave w fills rows w*8..w*8+7 ----
  {
    int c = lane & 7;
    int rr = wave * 8 + (lane >> 3);
    int g = m0 + rr;
    int gc = (g < n) ? g : (n - 1);
    #pragma unroll
    for (int rel = 0; rel < NM; rel++) {
      const u16* S  = (rel == 0) ? S0 : (rel == 1) ? S1 : S2;
      const int* of = (rel == 0) ? of0 : (rel == 1) ? of1 : of2;
      const int* ix = (rel == 0) ? ix0 : (rel == 1) ? ix1 : ix2;
      u32 ns = (u32)((rel == 0) ? ns0 : (rel == 1) ? ns1 : ns2);
      int e0 = of[gc], e1 = of[gc + 1];
      int deg = e1 - e0;
      float a[8] = {0.f, 0.f, 0.f, 0.f, 0.f, 0.f, 0.f, 0.f};
      for (int base = e0; __any(base < e1); base += 8) {
        int id[8];
        #pragma unroll
        for (int j = 0; j < 8; j++) {        // 8 independent 4B id loads
          int e = base + j;
          id[j] = (e < e1) ? ix[e] : -1;     // exec-masked load
        }
        #pragma unroll
        for (int j = 0; j < 8; j++) {        // 8 independent 16B row loads
          bf16x8 v = {};
          if ((u32)id[j] < ns)               // exec-masked: no fetch if inactive
            v = *(const bf16x8*)(S + (size_t)(u32)id[j] * 64 + c * 8);
          #pragma unroll
          for (int k = 0; k < 8; k++) a[k] += bf2f((u16)v[k]);
        }
      }
      float inv = (deg > 0) ? 1.f / (float)deg : 0.f;
      bf16x8 m8;
      #pragma unroll
      for (int k = 0; k < 8; k++) m8[k] = (short)f2bf(a[k] * inv);
      *(bf16x8*)&A_lds[rr * AP + rel * 64 + c * 8] = m8;
    }
    // root X row (16B vector copy)
    bf16x8 xv = *(const bf16x8*)(X + (size_t)gc * 64 + c * 8);
    *(bf16x8*)&A_lds[rr * AP + NM * 64 + c * 8] = xv;
  }
  __syncthreads();

  // ---- MFMA phase: wave w -> rows (w&1)*16..+16, cols (w>>1)*32..+32 ----
  int col0 = lane & 15, kb = lane >> 4;
  int rt = (wave & 1) * 16;
  int ct = (wave >> 1) * 32;
  const u16* Wbase[KC];
  #pragma unroll
  for (int kc = 0; kc < KC; kc++) {
    int m = kc >> 1;
    const u16* basep = (m < NM) ? ((m == 0) ? lin0 : (m == 1) ? lin1 : lin2) : root;
    Wbase[kc] = basep + (kc & 1) * 32 + kb * 8;
  }
  f32x4 acc0 = {}, acc1 = {};
  #pragma unroll
  for (int kc = 0; kc < KC; kc++) {
    bf16x8 Af = *(const bf16x8*)&A_lds[(rt + col0) * AP + kc * 32 + kb * 8];
    bf16x8 B0 = *(const bf16x8*)(Wbase[kc] + (ct + col0) * 64);        // L1 hot
    acc0 = __builtin_amdgcn_mfma_f32_16x16x32_bf16(Af, B0, acc0, 0, 0, 0);
    bf16x8 B1 = *(const bf16x8*)(Wbase[kc] + (ct + 16 + col0) * 64);
    acc1 = __builtin_amdgcn_mfma_f32_16x16x32_bf16(Af, B1, acc1, 0, 0, 0);
  }

  // ---- epilogue: v = relu((acc+b)*s) + x; read residuals FIRST, then
  // overwrite A_lds's low region with the D tile (one extra barrier) ----
  float b0 = bsum[ct + col0];
  float b1 = bsum[ct + 16 + col0];
  #pragma unroll
  for (int j = 0; j < 4; j++) {
    int dr = rt + kb * 4 + j;                // D row within 32-row tile
    float xv0 = bf2f(A_lds[dr * AP + NM * 64 + ct + col0]);
    acc0[j] = fmaxf((acc0[j] + b0) * scale, 0.f) + xv0;
    float xv1 = bf2f(A_lds[dr * AP + NM * 64 + ct + 16 + col0]);
    acc1[j] = fmaxf((acc1[j] + b1) * scale, 0.f) + xv1;
  }
  __syncthreads();                           // all residual reads complete
  u16* D = A_lds;                            // reuse: D range [0, 32*72) u16
  #pragma unroll
  for (int j = 0; j < 4; j++) {
    int dr = rt + kb * 4 + j;
    D[dr * 72 + ct + col0] = f2bf(acc0[j]);
    D[dr * 72 + ct + 16 + col0] = f2bf(acc1[j]);
  }
  __syncthreads();
  int row32 = t >> 3, cc = (t & 7) * 8;      // 256 threads = 32 rows x 8 chunks
  int row = m0 + row32;
  if (row < n) {
    bf16x8 o8;
    #pragma unroll
    for (int j = 0; j < 8; j++) o8[j] = (short)D[row32 * 72 + cc + j];
    *(bf16x8*)(out + (size_t)row * 64 + cc) = o8;       // 16B coalesced store
  }
}

// ---------------------------------------------------------------------------
// Column sums over bf16 features (graph-mean readout), vectorized.
__global__ void __launch_bounds__(256) colsum3(const u16* __restrict__ x, int n,
                                               float* __restrict__ gout) {
  __shared__ float part[64];
  int t = threadIdx.x;
  if (t < 64) part[t] = 0.f;
  __syncthreads();
  int lane = t & 63;
  int c = (lane & 7) * 8;
  int rs = blockIdx.x * 32 + (t >> 3);
  int stride = gridDim.x * 32;
  float a[8] = {0.f, 0.f, 0.f, 0.f, 0.f, 0.f, 0.f, 0.f};
  for (int r = rs; r < n; r += stride) {
    bf16x8 v = *(const bf16x8*)(x + (size_t)r * 64 + c);
    #pragma unroll
    for (int k = 0; k < 8; k++) a[k] += bf2f((u16)v[k]);
  }
  #pragma unroll
  for (int k = 0; k < 8; k++) {
    a[k] += __shfl_xor(a[k], 8);
    a[k] += __shfl_xor(a[k], 16);
    a[k] += __shfl_xor(a[k], 32);
  }
  if (lane < 8) {
    #pragma unroll
    for (int k = 0; k < 8; k++) atomicAdd(&part[lane * 8 + k], a[k]);
  }
  __syncthreads();
  if (t < 64) atomicAdd(&gout[t], part[t]);
}

// Crime head: out[0:20) as FP32
__global__ void __launch_bounds__(256) head2(const float* __restrict__ gsum,
    const float* __restrict__ Wc1, const float* __restrict__ bc1,
    const float* __restrict__ Wc2, const float* __restrict__ bc2,
    int NP, int NO, int NL, float* __restrict__ out) {
  __shared__ float g[192];
  __shared__ float h[64];
  int t = threadIdx.x;
  if (t < 192) {
    float d = (t < 64) ? (float)NP : (t < 128) ? (float)NO : (float)NL;
    g[t] = gsum[t] / d;
  }
  __syncthreads();
  if (t < 64) {
    float a = bc1[t];
    for (int k = 0; k < 192; k++) a += g[k] * Wc1[(size_t)t * 192 + k];
    h[t] = fmaxf(a, 0.f);
  }
  __syncthreads();
  if (t < 20) {
    float a = bc2[t];
    for (int k = 0; k < 64; k++) a += h[k] * Wc2[(size_t)t * 64 + k];
    out[t] = a;
  }
}

// Suspect head: out[i] as FP32 (out passed pre-offset by +20).
__global__ void __launch_bounds__(256) suspect2(const u16* __restrict__ p,
    const float* __restrict__ Ws1, const float* __restrict__ bs1,
    const float* __restrict__ Ws2, const float* __restrict__ bs2,
    float* __restrict__ out, int NP) {
  __shared__ float W1[2048];
  __shared__ float b1[32], w2[32];
  __shared__ float b2s;
  int t = threadIdx.x;
  #pragma unroll
  for (int i = 0; i < 8; i++) {
    int d = t + i * 256;
    W1[d] = Ws1[d];
  }
  if (t < 32) { b1[t] = bs1[t]; w2[t] = Ws2[t]; }
  if (t == 0) b2s = bs2[0];
  __syncthreads();
  int i = blockIdx.x * 256 + t;
  if (i >= NP) return;
  float x[64];
  #pragma unroll
  for (int q = 0; q < 8; q++) {
    bf16x8 v = *(const bf16x8*)(p + (size_t)i * 64 + q * 8);
    #pragma unroll
    for (int k = 0; k < 8; k++) x[q * 8 + k] = bf2f((u16)v[k]);
  }
  float sc = b2s;
  for (int j = 0; j < 32; j++) {
    float a = b1[j];
    const float* wr = &W1[j * 64];
    #pragma unroll
    for (int k = 0; k < 64; k++) a += x[k] * wr[k];
    sc += fmaxf(a, 0.f) * w2[j];
  }
  out[i] = sc;
}

// ---------------------------------------------------------------------------
extern "C" void kernel_launch(void* const* d_in, const int* in_sizes, int n_in,
                              void* d_out, int out_size, void* d_ws, size_t ws_size,
                              hipStream_t stream) {
  const int NP = in_sizes[0], NO = in_sizes[1], NL = in_sizes[2];
  const int Ea = in_sizes[3], Eu = in_sizes[5], Et = in_sizes[7];
  const int VP = in_sizes[9] / 64, VO = in_sizes[10] / 64, VL = in_sizes[11] / 64;

  const int* x_person   = (const int*)d_in[0];
  const int* x_object   = (const int*)d_in[1];
  const int* x_location = (const int*)d_in[2];
  const int* acts_src = (const int*)d_in[3];
  const int* acts_dst = (const int*)d_in[4];
  const int* uses_src = (const int*)d_in[5];
  const int* uses_dst = (const int*)d_in[6];
  const int* at_src   = (const int*)d_in[7];
  const int* at_dst   = (const int*)d_in[8];
  const float* person_emb   = (const float*)d_in[9];
  const float* object_emb   = (const float*)d_in[10];
  const float* location_emb = (const float*)d_in[11];
  const float* Wl  = (const float*)d_in[12];
  const float* bl  = (const float*)d_in[13];
  const float* Wr  = (const float*)d_in[14];
  const float* Wc1 = (const float*)d_in[15];
  const float* bc1 = (const float*)d_in[16];
  const float* Wc2 = (const float*)d_in[17];
  const float* bc2 = (const float*)d_in[18];
  const float* Ws1 = (const float*)d_in[19];
  const float* bs1 = (const float*)d_in[20];
  const float* Ws2 = (const float*)d_in[21];
  const float* bs2 = (const float*)d_in[22];
  float* out = (float*)d_out;

  // ---- bucket geometry (MAXBK guard: bench is 368) ----
  int B0 = (NP + BKW - 1) >> BKSH;
  int B1 = (NO + BKW - 1) >> BKSH;
  int B3 = (NL + BKW - 1) >> BKSH;
  int s1 = B0, s2 = s1 + B1, s3 = s2 + B0, s4 = s3 + B3, NBK = s4 + B0;
  if (NBK > MAXBK) return;   // out stays 0 -> visible failure signature

  // ---- workspace (16B aligned) ----
  char* w = (char*)d_ws;
  auto alloc = [&](size_t bytes) { char* r = w; w += (bytes + 15) & ~(size_t)15; return r; };
  u16* pA = (u16*)alloc((size_t)NP * 128);
  u16* pB = (u16*)alloc((size_t)NP * 128);
  u16* oA = (u16*)alloc((size_t)NO * 128);
  u16* oB = (u16*)alloc((size_t)NO * 128);
  u16* lA = (u16*)alloc((size_t)NL * 128);
  u16* lB = (u16*)alloc((size_t)NL * 128);
  float* gsum = (float*)alloc(192 * 4);
  const size_t CN = (size_t)3 * NP + NO + NL;
  int* off = (int*)alloc((CN + 8) * 4);
  int* bcnt  = (int*)alloc((MAXBK) * 4);
  int* bbase = (int*)alloc((MAXBK + 1) * 4);
  int* bcur  = (int*)alloc((MAXBK) * 4);
  const int E1 = Ea, E2 = E1 + Eu, E3 = E2 + Eu, E4 = E3 + Et, E5 = E4 + Et;
  u32* bdata = (u32*)alloc((size_t)E5 * 4);
  u16* WBlin  = (u16*)alloc((size_t)3 * 5 * 4096 * 2);
  u16* WBroot = (u16*)alloc((size_t)3 * 3 * 4096 * 2);
  float* bsums = (float*)alloc((size_t)3 * 3 * 64 * 4);
  int* csr = (int*)alloc((size_t)E5 * 4);
  size_t base_need = (size_t)(w - (char*)d_ws);
  (void)n_in; (void)out_size;
  // ws guard: if it fires, out stays 0 -> absmax == 0.118652 exactly (signature)
  if (base_need > ws_size) return;

  int o0 = 0, o1 = NP + 1, o2 = o1 + NO + 1, o3 = o2 + NP + 1, o4 = o3 + NL + 1;
  int g1 = Ea, g2 = Ea + Eu, g3 = Ea + 2 * Eu, g4 = Ea + 2 * Eu + Et;
  int* csr0 = csr;
  int* csr1 = csr + g1;
  int* csr2 = csr + g2;
  int* csr3 = csr + g3;
  int* csr4 = csr + g4;

  hipMemsetAsync(bcnt, 0, MAXBK * sizeof(int), stream);
  hipMemsetAsync(gsum, 0, 192 * sizeof(float), stream);

  prep_w<<<387, 256, 0, stream>>>(Wl, Wr, bl, WBlin, WBroot, bsums);

  int tg = (NP + NO + NL) * 16;
  gather3<<<(tg + 255) / 256, 256, 0, stream>>>(
      person_emb, x_person, pA, NP, VP,
      object_emb, x_object, oA, NO, VO,
      location_emb, x_location, lA, NL, VL);

  // ---- CSR build: bucket-sort (dense writes) ----
  bkt_count<<<(E5 + 8191) / 8192, 256, 0, stream>>>(
      acts_dst, uses_dst, uses_src, at_dst, at_src, bcnt,
      E1, E2, E3, E4, E5, s1, s2, s3, s4, NP, NO, NP, NL, NP, NBK);
  bkt_scan<<<1, 512, 0, stream>>>(bcnt, bbase, bcur, off,
      s1, s2, s3, s4, NBK,
      o0 + NP, o1 + NO, o2 + NP, o3 + NL, o4 + NP);
  bkt_scatter<<<(E5 + 4095) / 4096, 256, 0, stream>>>(
      acts_src, uses_src, uses_dst, at_src, at_dst,
      acts_dst, uses_dst, uses_src, at_dst, at_src,
      bcur, bdata, E1, E2, E3, E4, E5, s1, s2, s3, s4, NP, NO, NP, NL, NP, NBK);
  bkt_sort<<<NBK, 1024, 0, stream>>>(bbase, bdata, off, csr,
      s1, s2, s3, s4, NBK, NP, NO, NP, NL, NP,
      o1, o2, o3, o4, g1, g2, g3, g4, Ea, Eu, Et);

  // ---- 3 layers: fused gather+GEMM, ping-pong buffers ----
  u16* pb[2] = {pA, pB};
  u16* ob[2] = {oA, oB};
  u16* lb[2] = {lA, lB};
  int cu = 0;
  for (int t = 0; t < 3; t++) {
    u16 *pi = pb[cu], *po = pb[1 - cu];
    u16 *oi = ob[cu], *oo = ob[1 - cu];
    u16 *li = lb[cu], *lo = lb[1 - cu];
    sage_fused<3><<<(NP + 31) / 32, 256, 0, stream>>>(pi, po,
        pi, off + o0, csr0, NP,
        oi, off + o2, csr2, NO,
        li, off + o4, csr4, NL,
        WBlin + ((size_t)t * 5 + 0) * 4096,
        WBlin + ((size_t)t * 5 + 2) * 4096,
        WBlin + ((size_t)t * 5 + 4) * 4096,
        WBroot + ((size_t)t * 3 + 0) * 4096,
        bsums + ((size_t)t * 3 + 0) * 64, 1.f / 3.f, NP);
    sage_fused<1><<<(NO + 31) / 32, 256, 0, stream>>>(oi, oo,
        pi, off + o1, csr1, NP,
        (const u16*)0, (const int*)0, (const int*)0, 0,
        (const u16*)0, (const int*)0, (const int*)0, 0,
        WBlin + ((size_t)t * 5 + 1) * 4096, (const u16*)0, (const u16*)0,
        WBroot + ((size_t)t * 3 + 1) * 4096,
        bsums + ((size_t)t * 3 + 1) * 64, 1.f, NO);
    sage_fused<1><<<(NL + 31) / 32, 256, 0, stream>>>(li, lo,
        pi, off + o3, csr3, NP,
        (const u16*)0, (const int*)0, (const int*)0, 0,
        (const u16*)0, (const int*)0, (const int*)0, 0,
        WBlin + ((size_t)t * 5 + 3) * 4096, (const u16*)0, (const u16*)0,
        WBroot + ((size_t)t * 3 + 2) * 4096,
        bsums + ((size_t)t * 3 + 2) * 64, 1.f, NL);
    cu = 1 - cu;
  }
  const u16* pF = pb[cu];
  const u16* oF = ob[cu];
  const u16* lF = lb[cu];

  // ---- readout (FP32 output) ----
  colsum3<<<256, 256, 0, stream>>>(pF, NP, gsum);
  colsum3<<<128, 256, 0, stream>>>(oF, NO, gsum + 64);
  colsum3<<<64, 256, 0, stream>>>(lF, NL, gsum + 128);
  head2<<<1, 256, 0, stream>>>(gsum, Wc1, bc1, Wc2, bc2, NP, NO, NL, out);
  suspect2<<<(NP + 255) / 256, 256, 0, stream>>>(pF, Ws1, bs1, Ws2, bs2, out + 20, NP);
}